// Round 12
// baseline (939.905 us; speedup 1.0000x reference)
//
#include <hip/hip_runtime.h>
#include <cstdint>

typedef float f32x4 __attribute__((ext_vector_type(4)));
typedef __bf16 bf16x8 __attribute__((ext_vector_type(8)));
typedef unsigned int uint32;
typedef unsigned short ushort_t;

__device__ __forceinline__ ushort_t f2bf(float f) {
    uint32 u = __builtin_bit_cast(uint32, f);
    u = (u + 0x7fffu + ((u >> 16) & 1u)) >> 16;   // RNE
    return (ushort_t)u;
}
__device__ __forceinline__ float bf2f(ushort_t h) {
    return __builtin_bit_cast(float, (uint32)h << 16);
}

// ---------------------------------------------------------------------------
// im2col for conv1: NCHW fp32 -> P[px][32] bf16 patches (27 taps + 5 zero pad)
// ---------------------------------------------------------------------------
__global__ __launch_bounds__(256) void im2col1_kernel(
    const float* __restrict__ in,   // [4][3][512][512]
    ushort_t* __restrict__ P)       // [4*512*512][32]
{
    int px = blockIdx.x * 256 + threadIdx.x;
    int n = px >> 18, rem = px & 262143;
    int y = rem >> 9, x = rem & 511;
    ushort_t pv[32];
#pragma unroll
    for (int ci = 0; ci < 3; ++ci)
#pragma unroll
        for (int t = 0; t < 9; ++t) {
            int dy = t / 3 - 1, dx = t % 3 - 1;
            int yy = y + dy, xx = x + dx;
            bool v = ((unsigned)yy < 512u) && ((unsigned)xx < 512u);
            pv[ci * 9 + t] = v ? f2bf(in[((n * 3 + ci) * 512 + yy) * 512 + xx])
                               : (ushort_t)0;
        }
#pragma unroll
    for (int k = 27; k < 32; ++k) pv[k] = 0;
    uint4* dst = (uint4*)(P + (size_t)px * 32);
    dst[0] = *(uint4*)(pv);
    dst[1] = *(uint4*)(pv + 8);
    dst[2] = *(uint4*)(pv + 16);
    dst[3] = *(uint4*)(pv + 24);
}

// ---------------------------------------------------------------------------
// conv1 weights -> MFMA-A fragment order [nt][lane][8], K padded 27->32
// ---------------------------------------------------------------------------
__global__ void prepw1_kernel(const float* __restrict__ w1,
                              ushort_t* __restrict__ Wsw1)
{
    int i = blockIdx.x * 256 + threadIdx.x;   // 2048 total
    int ii = i & 7, lane = (i >> 3) & 63, nt = i >> 9;
    int cout = nt * 16 + (lane & 15);
    int k = (lane >> 4) * 8 + ii;
    Wsw1[i] = (k < 27) ? f2bf(w1[cout * 27 + k]) : (ushort_t)0;
}

// ---------------------------------------------------------------------------
// gemm1: X1[px][64] = W1[64][32] @ P[px][32]^T + b1 + fused BN stats
// ---------------------------------------------------------------------------
__global__ __launch_bounds__(256) void gemm1_kernel(
    const ushort_t* __restrict__ P,     // [Mpx][32]
    const ushort_t* __restrict__ Wsw1,  // [4][64][8]
    const float* __restrict__ b1,
    ushort_t* __restrict__ X1,          // [Mpx][64]
    float* __restrict__ stats)          // [32][128]
{
    __shared__ float sred[4][128];
    int tid = threadIdx.x;
    int wave = tid >> 6, lane = tid & 63;
    int lp = lane & 15, lg = lane >> 4;
    int pxb = blockIdx.x * 256 + wave * 64;

    bf16x8 wf[4];
#pragma unroll
    for (int nt = 0; nt < 4; ++nt)
        wf[nt] = *(const bf16x8*)(Wsw1 + (nt * 64 + lane) * 8);

    f32x4 acc[4][4];
#pragma unroll
    for (int a = 0; a < 4; ++a)
#pragma unroll
        for (int b = 0; b < 4; ++b) acc[a][b] = (f32x4){0.f, 0.f, 0.f, 0.f};

#pragma unroll
    for (int nf = 0; nf < 4; ++nf) {
        bf16x8 bfrag = *(const bf16x8*)(P + (size_t)(pxb + nf * 16 + lp) * 32 + lg * 8);
#pragma unroll
        for (int nt = 0; nt < 4; ++nt)
            acc[nt][nf] = __builtin_amdgcn_mfma_f32_16x16x32_bf16(
                wf[nt], bfrag, acc[nt][nf], 0, 0, 0);
    }

    float s16[16], q16[16];
#pragma unroll
    for (int j = 0; j < 16; ++j) { s16[j] = 0.f; q16[j] = 0.f; }

#pragma unroll
    for (int nf = 0; nf < 4; ++nf) {
        size_t px = (size_t)pxb + nf * 16 + lp;
#pragma unroll
        for (int nt = 0; nt < 4; ++nt) {
            ushort_t ov[4];
#pragma unroll
            for (int r = 0; r < 4; ++r) {
                float o = acc[nt][nf][r] + b1[nt * 16 + lg * 4 + r];
                s16[nt * 4 + r] += o;
                q16[nt * 4 + r] += o * o;
                ov[r] = f2bf(o);
            }
            *(ushort4*)(X1 + px * 64 + nt * 16 + lg * 4) = *(ushort4*)ov;
        }
    }

#pragma unroll
    for (int off = 1; off < 16; off <<= 1)
#pragma unroll
        for (int j = 0; j < 16; ++j) {
            s16[j] += __shfl_xor(s16[j], off);
            q16[j] += __shfl_xor(q16[j], off);
        }
    if (lp == 0) {
#pragma unroll
        for (int nt = 0; nt < 4; ++nt)
#pragma unroll
            for (int r = 0; r < 4; ++r) {
                int ch = nt * 16 + lg * 4 + r;
                sred[wave][ch]      = s16[nt * 4 + r];
                sred[wave][64 + ch] = q16[nt * 4 + r];
            }
    }
    __syncthreads();
    if (tid < 128) {
        float tot = sred[0][tid] + sred[1][tid] + sred[2][tid] + sred[3][tid];
        atomicAdd(&stats[(blockIdx.x & 31) * 128 + tid], tot);
    }
}

// ---------------------------------------------------------------------------
// finalize: sum 32 buckets -> scale/shift
// ---------------------------------------------------------------------------
__global__ void finalize_kernel(const float* __restrict__ stats,
                                const float* __restrict__ gamma,
                                const float* __restrict__ beta,
                                float inv_cnt, float* __restrict__ scsh)
{
    int c = threadIdx.x;  // 64
    float S = 0.f, Q = 0.f;
    for (int b = 0; b < 32; ++b) {
        S += stats[b * 128 + c];
        Q += stats[b * 128 + 64 + c];
    }
    float mean = S * inv_cnt;
    float var  = Q * inv_cnt - mean * mean;
    float rs   = rsqrtf(var + 1e-5f);
    float sc   = gamma[c] * rs;
    scsh[c]      = sc;
    scsh[64 + c] = beta[c] - mean * sc;
}

// ---------------------------------------------------------------------------
// weight swizzle into MFMA-A fragment order: [tap][kc][nt][lane][8]
// value = w[cout][cin][tap] * scale[cin]  (scale==null -> 1)
// ---------------------------------------------------------------------------
__global__ __launch_bounds__(256) void prepw_kernel(
    const float* __restrict__ w, const float* __restrict__ scale,
    ushort_t* __restrict__ Wsw, int CIN)
{
    int i = blockIdx.x * 256 + threadIdx.x;
    int KC = CIN >> 5;
    int ii = i & 7, lane = (i >> 3) & 63, nt = (i >> 9) & 3;
    int rest = i >> 11;
    int kc = rest % KC, t = rest / KC;
    if (t >= 9) return;
    int cout = nt * 16 + (lane & 15);
    int cin  = kc * 32 + (lane >> 4) * 8 + ii;
    float v = w[(cout * CIN + cin) * 9 + t];
    if (scale) v *= scale[cin];
    Wsw[i] = f2bf(v);
}

// T[t][cout] = sum_cin w2[cout][cin][t] * shift[cin]; Tsum[cout] at T+576
__global__ void prepT_kernel(const float* __restrict__ w2,
                             const float* __restrict__ shift,
                             float* __restrict__ T)
{
    int idx = threadIdx.x;   // 576
    if (idx < 576) {
        int t = idx / 64, cout = idx % 64;
        float s = 0.f;
        for (int cin = 0; cin < 64; ++cin)
            s += w2[(cout * 64 + cin) * 9 + t] * shift[cin];
        T[idx] = s;
    }
    __syncthreads();
    if (idx < 64) {
        float s = 0.f;
        for (int t = 0; t < 9; ++t) s += T[t * 64 + idx];
        T[576 + idx] = s;
    }
}

// ---------------------------------------------------------------------------
// R5 production conv: LDS-tiled implicit-GEMM conv 3x3 SAME, CIN->64.
// Plane-major LDS [4][396][8ch], 2 barriers/chunk, fused BN stats.
// ---------------------------------------------------------------------------
template <int CIN, bool HAS_T, int HH, int WW>
__global__ __launch_bounds__(256, 4) void conv_mfma4_kernel(
    const ushort_t* __restrict__ X,    // NHWC bf16 [N*H*W][CIN]
    const ushort_t* __restrict__ Wsw,  // [9][CIN/32][4][64][8]
    const float* __restrict__ T,       // [9*64 + 64] or null
    const float* __restrict__ bias,    // [64]
    ushort_t* __restrict__ Y,          // NHWC bf16 [N*H*W][64]
    float* __restrict__ stats)         // [32][128]
{
    constexpr int KC     = CIN >> 5;
    constexpr int COLS_B = WW >> 6;
    constexpr int ROWS_B = HH >> 2;

    __shared__ ushort_t tile[12672];   // [4][396][8] = 25344 B
    __shared__ float sred[4][128];

    int nwg = gridDim.x;
    int bid = blockIdx.x;
    int cpx = nwg >> 3;
    int bs  = (bid & 7) * cpx + (bid >> 3);

    int tid  = threadIdx.x;
    int wave = tid >> 6, lane = tid & 63;
    int lp = lane & 15, lg = lane >> 4;

    int tmp = bs;
    int ctile = tmp % COLS_B;  tmp /= COLS_B;
    int rtile = tmp % ROWS_B;
    int n     = tmp / ROWS_B;
    int y0 = rtile << 2, x0 = ctile << 6;
    int y  = y0 + wave;

    f32x4 acc[4][4];
#pragma unroll
    for (int a = 0; a < 4; ++a)
#pragma unroll
        for (int b = 0; b < 4; ++b) acc[a][b] = (f32x4){0.f, 0.f, 0.f, 0.f};

#pragma unroll 1
    for (int c = 0; c < KC; ++c) {
        if (c) __syncthreads();
#pragma unroll
        for (int j = 0; j < 7; ++j) {
            int s = tid + j * 256;
            if (s < 1584) {
                int px = s >> 2, cb = s & 3;
                int ry = px / 66, cx = px - ry * 66;
                int gy = y0 - 1 + ry, gx = x0 - 1 + cx;
                uint4 v = {0u, 0u, 0u, 0u};
                if (((unsigned)gy < (unsigned)HH) && ((unsigned)gx < (unsigned)WW))
                    v = *(const uint4*)(X + ((size_t)(n * HH + gy) * WW + gx) * CIN
                                          + c * 32 + cb * 8);
                *(uint4*)(tile + cb * 3168 + px * 8) = v;
            }
        }
        __syncthreads();

#pragma unroll
        for (int t = 0; t < 9; ++t) {
            const int dy = t / 3 - 1, dx = t % 3 - 1;
            bf16x8 wf[4];
#pragma unroll
            for (int nt = 0; nt < 4; ++nt)
                wf[nt] = *(const bf16x8*)(Wsw + (size_t)(((t * KC + c) << 2) + nt) * 512 + lane * 8);
            int prow = (wave + 1 + dy) * 66 + (1 + dx) + lp;
#pragma unroll
            for (int nf = 0; nf < 4; ++nf) {
                int px = prow + nf * 16;
                bf16x8 bfrag = *(const bf16x8*)(tile + lg * 3168 + px * 8);
#pragma unroll
                for (int nt = 0; nt < 4; ++nt)
                    acc[nt][nf] = __builtin_amdgcn_mfma_f32_16x16x32_bf16(
                        wf[nt], bfrag, acc[nt][nf], 0, 0, 0);
            }
        }
    }

    bool top = (y == 0), bot = (y == HH - 1);
    float s16[16], q16[16];
#pragma unroll
    for (int j = 0; j < 16; ++j) { s16[j] = 0.f; q16[j] = 0.f; }

    size_t rowbase = ((size_t)(n * HH + y) * WW) * 64;
#pragma unroll
    for (int nf = 0; nf < 4; ++nf) {
        int x = x0 + nf * 16 + lp;
        bool lft = (x == 0), rgt = (x == WW - 1);
        bool edge = top | bot | lft | rgt;
#pragma unroll
        for (int nt = 0; nt < 4; ++nt) {
            ushort_t ov[4];
#pragma unroll
            for (int r = 0; r < 4; ++r) {
                int ch = nt * 16 + lg * 4 + r;
                float o = acc[nt][nf][r] + bias[ch];
                if (HAS_T) {
                    o += T[576 + ch];
                    if (edge) {
#pragma unroll
                        for (int t = 0; t < 9; ++t) {
                            int dy = t / 3 - 1, dx = t % 3 - 1;
                            bool miss = (top && dy < 0) || (bot && dy > 0) ||
                                        (lft && dx < 0) || (rgt && dx > 0);
                            if (miss) o -= T[t * 64 + ch];
                        }
                    }
                }
                s16[nt * 4 + r] += o;
                q16[nt * 4 + r] += o * o;
                ov[r] = f2bf(o);
            }
            *(ushort4*)(Y + rowbase + (size_t)x * 64 + nt * 16 + lg * 4) = *(ushort4*)ov;
        }
    }

#pragma unroll
    for (int off = 1; off < 16; off <<= 1)
#pragma unroll
        for (int j = 0; j < 16; ++j) {
            s16[j] += __shfl_xor(s16[j], off);
            q16[j] += __shfl_xor(q16[j], off);
        }
    if (lp == 0) {
#pragma unroll
        for (int nt = 0; nt < 4; ++nt)
#pragma unroll
            for (int r = 0; r < 4; ++r) {
                int ch = nt * 16 + lg * 4 + r;
                sred[wave][ch]      = s16[nt * 4 + r];
                sred[wave][64 + ch] = q16[nt * 4 + r];
            }
    }
    __syncthreads();
    if (tid < 128) {
        float tot = sred[0][tid] + sred[1][tid] + sred[2][tid] + sred[3][tid];
        atomicAdd(&stats[(bs & 31) * 128 + tid], tot);
    }
}

// ---------------------------------------------------------------------------
// PROBE 1: stage-only, x3 iterations. Same addresses/LDS layout/barrier
// rhythm as conv_mfma4<64,...,512,512>. No MFMA, no weights, no epilogue.
// ---------------------------------------------------------------------------
__global__ __launch_bounds__(256, 4) void probe_stage_kernel(
    const ushort_t* __restrict__ X, uint32* __restrict__ scratch)
{
    __shared__ ushort_t tile[12672];
    int nwg = gridDim.x, bid = blockIdx.x, cpx = nwg >> 3;
    int bs = (bid & 7) * cpx + (bid >> 3);
    int tid = threadIdx.x;
    int tmp = bs;
    int ctile = tmp % 8;  tmp /= 8;
    int rtile = tmp % 128;
    int n     = tmp / 128;
    int y0 = rtile << 2, x0 = ctile << 6;

    uint32 csum = 0;
#pragma unroll 1
    for (int it = 0; it < 3; ++it) {
#pragma unroll 1
        for (int c = 0; c < 2; ++c) {
            __syncthreads();
#pragma unroll
            for (int j = 0; j < 7; ++j) {
                int s = tid + j * 256;
                if (s < 1584) {
                    int px = s >> 2, cb = s & 3;
                    int ry = px / 66, cx = px - ry * 66;
                    int gy = y0 - 1 + ry, gx = x0 - 1 + cx;
                    uint4 v = {0u, 0u, 0u, 0u};
                    if (((unsigned)gy < 512u) && ((unsigned)gx < 512u))
                        v = *(const uint4*)(X + ((size_t)(n * 512 + gy) * 512 + gx) * 64
                                              + c * 32 + cb * 8);
                    *(uint4*)(tile + cb * 3168 + px * 8) = v;
                }
            }
            __syncthreads();
            csum ^= *(uint32*)(tile + ((tid * 2 + it + c) & 12670));
        }
    }
    scratch[(size_t)blockIdx.x * 256 + tid] = csum;
}

// ---------------------------------------------------------------------------
// PROBE 2/3: compute-only, x3 iterations. Stage chunk0 once (real data),
// then run the exact 9-tap x 16-MFMA loop per chunk with per-chunk barrier.
// HOIST=false: weights re-loaded from L2 per tap (as production).
// HOIST=true : weights loaded once (isolates the wf L2 chain).
// ---------------------------------------------------------------------------
template <bool HOIST>
__global__ __launch_bounds__(256, 4) void probe_cmp_kernel(
    const ushort_t* __restrict__ X, const ushort_t* __restrict__ Wsw,
    float* __restrict__ scratch)
{
    constexpr int KC = 2;
    __shared__ ushort_t tile[12672];
    int nwg = gridDim.x, bid = blockIdx.x, cpx = nwg >> 3;
    int bs = (bid & 7) * cpx + (bid >> 3);
    int tid = threadIdx.x, wave = tid >> 6, lane = tid & 63;
    int lp = lane & 15, lg = lane >> 4;
    int tmp = bs;
    int ctile = tmp % 8;  tmp /= 8;
    int rtile = tmp % 128;
    int n     = tmp / 128;
    int y0 = rtile << 2, x0 = ctile << 6;

    // one-time real stage (chunk 0)
#pragma unroll
    for (int j = 0; j < 7; ++j) {
        int s = tid + j * 256;
        if (s < 1584) {
            int px = s >> 2, cb = s & 3;
            int ry = px / 66, cx = px - ry * 66;
            int gy = y0 - 1 + ry, gx = x0 - 1 + cx;
            uint4 v = {0u, 0u, 0u, 0u};
            if (((unsigned)gy < 512u) && ((unsigned)gx < 512u))
                v = *(const uint4*)(X + ((size_t)(n * 512 + gy) * 512 + gx) * 64 + cb * 8);
            *(uint4*)(tile + cb * 3168 + px * 8) = v;
        }
    }
    __syncthreads();

    bf16x8 wfh[4];
    if (HOIST) {
#pragma unroll
        for (int nt = 0; nt < 4; ++nt)
            wfh[nt] = *(const bf16x8*)(Wsw + (size_t)nt * 512 + lane * 8);
    }

    f32x4 acc[4][4];
#pragma unroll
    for (int a = 0; a < 4; ++a)
#pragma unroll
        for (int b = 0; b < 4; ++b) acc[a][b] = (f32x4){0.f, 0.f, 0.f, 0.f};

#pragma unroll 1
    for (int it = 0; it < 3; ++it) {
#pragma unroll 1
        for (int c = 0; c < KC; ++c) {
#pragma unroll
            for (int t = 0; t < 9; ++t) {
                const int dy = t / 3 - 1, dx = t % 3 - 1;
                bf16x8 wf[4];
                if (HOIST) {
#pragma unroll
                    for (int nt = 0; nt < 4; ++nt) wf[nt] = wfh[nt];
                } else {
#pragma unroll
                    for (int nt = 0; nt < 4; ++nt)
                        wf[nt] = *(const bf16x8*)(Wsw
                            + (size_t)(((t * KC + c) << 2) + nt) * 512 + lane * 8);
                }
                int prow = (wave + 1 + dy) * 66 + (1 + dx) + lp;
#pragma unroll
                for (int nf = 0; nf < 4; ++nf) {
                    int px = prow + nf * 16;
                    bf16x8 bfrag = *(const bf16x8*)(tile + lg * 3168 + px * 8);
#pragma unroll
                    for (int nt = 0; nt < 4; ++nt)
                        acc[nt][nf] = __builtin_amdgcn_mfma_f32_16x16x32_bf16(
                            wf[nt], bfrag, acc[nt][nf], 0, 0, 0);
                }
            }
            __syncthreads();
        }
    }

    float s = 0.f;
#pragma unroll
    for (int a = 0; a < 4; ++a)
#pragma unroll
        for (int b = 0; b < 4; ++b)
#pragma unroll
            for (int r = 0; r < 4; ++r) s += acc[a][b][r];
    scratch[(size_t)blockIdx.x * 256 + tid] = s;
}

// ---------------------------------------------------------------------------
// BN2 + ReLU -> skip_con (NCHW fp32) + Haar DWT -> X3 (NHWC bf16, 256 ch)
// ---------------------------------------------------------------------------
__global__ __launch_bounds__(256) void bn2_dwt_skip_kernel(
    const ushort_t* __restrict__ X2, const float* __restrict__ scsh,
    float* __restrict__ skip,     // [4][64][512][512]
    ushort_t* __restrict__ X3)    // [4][256][256][256]
{
    __shared__ float v[128][65];
    int tid = threadIdx.x;
    int b = blockIdx.x;
    int n  = b >> 11;
    int r2 = b & 2047;
    int y0 = (r2 >> 3) << 1;
    int x0 = (r2 & 7) << 6;

#pragma unroll
    for (int k = 0; k < 4; ++k) {
        int q  = tid + k * 256;
        int px = q >> 3;
        int cb = (q & 7) * 8;
        int gy = y0 + (px >> 6);
        int gx = x0 + (px & 63);
        uint4 raw = *(const uint4*)(X2 + ((size_t)(n * 512 + gy) * 512 + gx) * 64 + cb);
        const ushort_t* up = (const ushort_t*)&raw;
#pragma unroll
        for (int j = 0; j < 8; ++j) {
            float f = bf2f(up[j]);
            float o = f * scsh[cb + j] + scsh[64 + cb + j];
            v[px][cb + j] = fmaxf(o, 0.f);
        }
    }
    __syncthreads();

    {
        int c = tid >> 2, sub = tid & 3;
#pragma unroll
        for (int rr = 0; rr < 2; ++rr) {
            float* orow = skip + ((size_t)(n * 64 + c) * 512 + (y0 + rr)) * 512 + x0;
#pragma unroll
            for (int qq = 0; qq < 4; ++qq) {
                int xb = qq * 16 + sub * 4;
                float4 w4;
                w4.x = v[rr * 64 + xb + 0][c];
                w4.y = v[rr * 64 + xb + 1][c];
                w4.z = v[rr * 64 + xb + 2][c];
                w4.w = v[rr * 64 + xb + 3][c];
                *(float4*)(orow + xb) = w4;
            }
        }
    }
    {
        int c = tid & 63, jj = tid >> 6;
        int yq = y0 >> 1, xq = x0 >> 1;
#pragma unroll
        for (int it = 0; it < 8; ++it) {
            int xl = jj * 8 + it;
            float x00 = v[2 * xl][c],      x01 = v[2 * xl + 1][c];
            float x10 = v[64 + 2 * xl][c], x11 = v[64 + 2 * xl + 1][c];
            float cA = (x00 + x01 + x10 + x11) * 0.5f;
            float cH = (x00 + x01 - x10 - x11) * 0.5f;
            float cV = (x00 - x01 + x10 - x11) * 0.5f;
            float cD = (x00 - x01 - x10 + x11) * 0.5f;
            ushort_t* dst = X3 + ((size_t)(n * 256 + yq) * 256 + xq + xl) * 256 + c;
            dst[0]   = f2bf(cA);
            dst[64]  = f2bf(cH);
            dst[128] = f2bf(cV);
            dst[192] = f2bf(cD);
        }
    }
}

// ---------------------------------------------------------------------------
// BN3 + ReLU -> dwt_out (NCHW fp32)
// ---------------------------------------------------------------------------
__global__ __launch_bounds__(256) void bn3_kernel(
    const ushort_t* __restrict__ X4, const float* __restrict__ scsh,
    float* __restrict__ out)   // [4][64][256][256]
{
    __shared__ float v[64][65];
    int tid = threadIdx.x;
    int b = blockIdx.x;
    int n  = b >> 10;
    int r2 = b & 1023;
    int y  = r2 >> 2;
    int x0 = (r2 & 3) << 6;

#pragma unroll
    for (int k = 0; k < 2; ++k) {
        int q  = tid + k * 256;
        int px = q >> 3;
        int cb = (q & 7) * 8;
        uint4 raw = *(const uint4*)(X4 + ((size_t)(n * 256 + y) * 256 + x0 + px) * 64 + cb);
        const ushort_t* up = (const ushort_t*)&raw;
#pragma unroll
        for (int j = 0; j < 8; ++j) {
            float f = bf2f(up[j]);
            float o = f * scsh[cb + j] + scsh[64 + cb + j];
            v[px][cb + j] = fmaxf(o, 0.f);
        }
    }
    __syncthreads();
    int c = tid >> 2, sub = tid & 3;
    float* orow = out + ((size_t)(n * 64 + c) * 256 + y) * 256 + x0;
#pragma unroll
    for (int qq = 0; qq < 4; ++qq) {
        int xb = qq * 16 + sub * 4;
        float4 w4;
        w4.x = v[xb + 0][c];
        w4.y = v[xb + 1][c];
        w4.z = v[xb + 2][c];
        w4.w = v[xb + 3][c];
        *(float4*)(orow + xb) = w4;
    }
}

// ---------------------------------------------------------------------------
extern "C" void kernel_launch(void* const* d_in, const int* in_sizes, int n_in,
                              void* d_out, int out_size, void* d_ws, size_t ws_size,
                              hipStream_t stream)
{
    const float* in  = (const float*)d_in[0];
    const float* w1  = (const float*)d_in[1];
    const float* b1  = (const float*)d_in[2];
    const float* g1  = (const float*)d_in[3];
    const float* be1 = (const float*)d_in[4];
    const float* w2  = (const float*)d_in[5];
    const float* b2  = (const float*)d_in[6];
    const float* g2  = (const float*)d_in[7];
    const float* be2 = (const float*)d_in[8];
    const float* w3  = (const float*)d_in[9];
    const float* b3  = (const float*)d_in[10];
    const float* g3  = (const float*)d_in[11];
    const float* be3 = (const float*)d_in[12];

    float* out     = (float*)d_out;
    float* dwt_out = out;              // 4*64*256*256
    float* skip    = out + 16777216;   // 4*64*512*512

    char* ws = (char*)d_ws;
    ushort_t* X1 = (ushort_t*)ws;                       // 134,217,728 B
    ushort_t* X2 = (ushort_t*)(ws + 134217728);         // 134,217,728 B
    ushort_t* P  = X2;                                  // im2col patches alias X2
    ushort_t* X3 = X1;                                  // reuse
    ushort_t* X4 = X2;                                  // reuse
    char* aux = ws + 268435456;
    float* stats1 = (float*)(aux);                      // 16384 B each
    float* stats2 = (float*)(aux + 16384);
    float* stats3 = (float*)(aux + 32768);
    float* scsh1  = (float*)(aux + 49152);
    float* scsh2  = (float*)(aux + 49664);
    float* scsh3  = (float*)(aux + 50176);
    float* T2     = (float*)(aux + 50688);              // 640 floats
    ushort_t* Wsw2 = (ushort_t*)(aux + 57344);          // 73,728 B
    ushort_t* Wsw3 = (ushort_t*)(aux + 131072);         // 294,912 B
    ushort_t* Wsw1 = (ushort_t*)(aux + 425984);         // 4,096 B

    // probe scratch (far past all live buffers; ws >= 1.3 GB per harness fill)
    uint32* pscr0 = (uint32*)(ws + 943718400);          // 4 MB
    float*  pscr1 = (float*)(ws + 952107008);
    float*  pscr2 = (float*)(ws + 960495616);

    hipMemsetAsync(aux, 0, 49152, stream);

    im2col1_kernel<<<4096, 256, 0, stream>>>(in, P);
    prepw1_kernel<<<8, 256, 0, stream>>>(w1, Wsw1);
    gemm1_kernel<<<4096, 256, 0, stream>>>(P, Wsw1, b1, X1, stats1);
    finalize_kernel<<<1, 64, 0, stream>>>(stats1, g1, be1, 1.f / 1048576.f, scsh1);
    prepw_kernel<<<144, 256, 0, stream>>>(w2, scsh1, Wsw2, 64);
    prepT_kernel<<<1, 576, 0, stream>>>(w2, scsh1 + 64, T2);

    conv_mfma4_kernel<64, true, 512, 512><<<4096, 256, 0, stream>>>(
        X1, Wsw2, T2, b2, X2, stats2);
    finalize_kernel<<<1, 64, 0, stream>>>(stats2, g2, be2, 1.f / 1048576.f, scsh2);

    bn2_dwt_skip_kernel<<<8192, 256, 0, stream>>>(X2, scsh2, skip, X3);

    prepw_kernel<<<576, 256, 0, stream>>>(w3, nullptr, Wsw3, 256);
    conv_mfma4_kernel<256, false, 256, 256><<<1024, 256, 0, stream>>>(
        X3, Wsw3, nullptr, b3, X4, stats3);
    finalize_kernel<<<1, 64, 0, stream>>>(stats3, g3, be3, 1.f / 262144.f, scsh3);

    bn3_kernel<<<4096, 256, 0, stream>>>(X4, scsh3, dwt_out);

    // ---- diagnostic probes (conv2 shape; outputs go to dead scratch) ----
    probe_stage_kernel<<<4096, 256, 0, stream>>>(X1, pscr0);
    probe_cmp_kernel<false><<<4096, 256, 0, stream>>>(X1, Wsw2, pscr1);
    probe_cmp_kernel<true><<<4096, 256, 0, stream>>>(X1, Wsw2, pscr2);
}

// Round 13
// 629.827 us; speedup vs baseline: 1.4923x; 1.4923x over previous
//
#include <hip/hip_runtime.h>
#include <cstdint>

typedef float f32x4 __attribute__((ext_vector_type(4)));
typedef __bf16 bf16x8 __attribute__((ext_vector_type(8)));
typedef unsigned int uint32;
typedef unsigned short ushort_t;

__device__ __forceinline__ ushort_t f2bf(float f) {
    uint32 u = __builtin_bit_cast(uint32, f);
    u = (u + 0x7fffu + ((u >> 16) & 1u)) >> 16;   // RNE
    return (ushort_t)u;
}
__device__ __forceinline__ float bf2f(ushort_t h) {
    return __builtin_bit_cast(float, (uint32)h << 16);
}

// async global->LDS, 16B per lane; lds dst = wave-uniform base + lane*16 (HW)
__device__ __forceinline__ void gload_lds16(const void* g, void* l) {
    __builtin_amdgcn_global_load_lds(
        (const __attribute__((address_space(1))) uint32*)g,
        (__attribute__((address_space(3))) uint32*)l, 16, 0, 0);
}

// ---------------------------------------------------------------------------
// im2col for conv1: NCHW fp32 -> P[px][32] bf16 patches (27 taps + 5 zero pad)
// ---------------------------------------------------------------------------
__global__ __launch_bounds__(256) void im2col1_kernel(
    const float* __restrict__ in,   // [4][3][512][512]
    ushort_t* __restrict__ P)       // [4*512*512][32]
{
    int px = blockIdx.x * 256 + threadIdx.x;
    int n = px >> 18, rem = px & 262143;
    int y = rem >> 9, x = rem & 511;
    ushort_t pv[32];
#pragma unroll
    for (int ci = 0; ci < 3; ++ci)
#pragma unroll
        for (int t = 0; t < 9; ++t) {
            int dy = t / 3 - 1, dx = t % 3 - 1;
            int yy = y + dy, xx = x + dx;
            bool v = ((unsigned)yy < 512u) && ((unsigned)xx < 512u);
            pv[ci * 9 + t] = v ? f2bf(in[((n * 3 + ci) * 512 + yy) * 512 + xx])
                               : (ushort_t)0;
        }
#pragma unroll
    for (int k = 27; k < 32; ++k) pv[k] = 0;
    uint4* dst = (uint4*)(P + (size_t)px * 32);
    dst[0] = *(uint4*)(pv);
    dst[1] = *(uint4*)(pv + 8);
    dst[2] = *(uint4*)(pv + 16);
    dst[3] = *(uint4*)(pv + 24);
}

// ---------------------------------------------------------------------------
// conv1 weights -> MFMA-A fragment order [nt][lane][8], K padded 27->32
// ---------------------------------------------------------------------------
__global__ void prepw1_kernel(const float* __restrict__ w1,
                              ushort_t* __restrict__ Wsw1)
{
    int i = blockIdx.x * 256 + threadIdx.x;   // 2048 total
    int ii = i & 7, lane = (i >> 3) & 63, nt = i >> 9;
    int cout = nt * 16 + (lane & 15);
    int k = (lane >> 4) * 8 + ii;
    Wsw1[i] = (k < 27) ? f2bf(w1[cout * 27 + k]) : (ushort_t)0;
}

// ---------------------------------------------------------------------------
// gemm1: X1[px][64] = W1[64][32] @ P[px][32]^T + b1 + fused BN stats
// ---------------------------------------------------------------------------
__global__ __launch_bounds__(256) void gemm1_kernel(
    const ushort_t* __restrict__ P,     // [Mpx][32]
    const ushort_t* __restrict__ Wsw1,  // [4][64][8]
    const float* __restrict__ b1,
    ushort_t* __restrict__ X1,          // [Mpx][64]
    float* __restrict__ stats)          // [32][128]
{
    __shared__ float sred[4][128];
    int tid = threadIdx.x;
    int wave = tid >> 6, lane = tid & 63;
    int lp = lane & 15, lg = lane >> 4;
    int pxb = blockIdx.x * 256 + wave * 64;

    bf16x8 wf[4];
#pragma unroll
    for (int nt = 0; nt < 4; ++nt)
        wf[nt] = *(const bf16x8*)(Wsw1 + (nt * 64 + lane) * 8);

    f32x4 acc[4][4];
#pragma unroll
    for (int a = 0; a < 4; ++a)
#pragma unroll
        for (int b = 0; b < 4; ++b) acc[a][b] = (f32x4){0.f, 0.f, 0.f, 0.f};

#pragma unroll
    for (int nf = 0; nf < 4; ++nf) {
        bf16x8 bfrag = *(const bf16x8*)(P + (size_t)(pxb + nf * 16 + lp) * 32 + lg * 8);
#pragma unroll
        for (int nt = 0; nt < 4; ++nt)
            acc[nt][nf] = __builtin_amdgcn_mfma_f32_16x16x32_bf16(
                wf[nt], bfrag, acc[nt][nf], 0, 0, 0);
    }

    float s16[16], q16[16];
#pragma unroll
    for (int j = 0; j < 16; ++j) { s16[j] = 0.f; q16[j] = 0.f; }

#pragma unroll
    for (int nf = 0; nf < 4; ++nf) {
        size_t px = (size_t)pxb + nf * 16 + lp;
#pragma unroll
        for (int nt = 0; nt < 4; ++nt) {
            ushort_t ov[4];
#pragma unroll
            for (int r = 0; r < 4; ++r) {
                float o = acc[nt][nf][r] + b1[nt * 16 + lg * 4 + r];
                s16[nt * 4 + r] += o;
                q16[nt * 4 + r] += o * o;
                ov[r] = f2bf(o);
            }
            *(ushort4*)(X1 + px * 64 + nt * 16 + lg * 4) = *(ushort4*)ov;
        }
    }

#pragma unroll
    for (int off = 1; off < 16; off <<= 1)
#pragma unroll
        for (int j = 0; j < 16; ++j) {
            s16[j] += __shfl_xor(s16[j], off);
            q16[j] += __shfl_xor(q16[j], off);
        }
    if (lp == 0) {
#pragma unroll
        for (int nt = 0; nt < 4; ++nt)
#pragma unroll
            for (int r = 0; r < 4; ++r) {
                int ch = nt * 16 + lg * 4 + r;
                sred[wave][ch]      = s16[nt * 4 + r];
                sred[wave][64 + ch] = q16[nt * 4 + r];
            }
    }
    __syncthreads();
    if (tid < 128) {
        float tot = sred[0][tid] + sred[1][tid] + sred[2][tid] + sred[3][tid];
        atomicAdd(&stats[(blockIdx.x & 31) * 128 + tid], tot);
    }
}

// ---------------------------------------------------------------------------
// finalize: sum 32 buckets -> scale/shift
// ---------------------------------------------------------------------------
__global__ void finalize_kernel(const float* __restrict__ stats,
                                const float* __restrict__ gamma,
                                const float* __restrict__ beta,
                                float inv_cnt, float* __restrict__ scsh)
{
    int c = threadIdx.x;  // 64
    float S = 0.f, Q = 0.f;
    for (int b = 0; b < 32; ++b) {
        S += stats[b * 128 + c];
        Q += stats[b * 128 + 64 + c];
    }
    float mean = S * inv_cnt;
    float var  = Q * inv_cnt - mean * mean;
    float rs   = rsqrtf(var + 1e-5f);
    float sc   = gamma[c] * rs;
    scsh[c]      = sc;
    scsh[64 + c] = beta[c] - mean * sc;
}

// ---------------------------------------------------------------------------
// weight swizzle into chunk-contiguous order: [kc][t][nt][lane][8]
// value = w[cout][cin][tap] * scale[cin]  (scale==null -> 1)
// ---------------------------------------------------------------------------
__global__ __launch_bounds__(256) void prepw_kernel(
    const float* __restrict__ w, const float* __restrict__ scale,
    ushort_t* __restrict__ Wsw, int CIN)
{
    int i = blockIdx.x * 256 + threadIdx.x;
    int KC = CIN >> 5;
    int ii = i & 7, lane = (i >> 3) & 63, nt = (i >> 9) & 3;
    int rest = i >> 11;               // kc*9 + t
    if (rest >= 9 * KC) return;
    int t = rest % 9, kc = rest / 9;
    int cout = nt * 16 + (lane & 15);
    int cin  = kc * 32 + (lane >> 4) * 8 + ii;
    float v = w[(cout * CIN + cin) * 9 + t];
    if (scale) v *= scale[cin];
    Wsw[i] = f2bf(v);
}

// T[t][cout] = sum_cin w2[cout][cin][t] * shift[cin]; Tsum[cout] at T+576
__global__ void prepT_kernel(const float* __restrict__ w2,
                             const float* __restrict__ shift,
                             float* __restrict__ T)
{
    int idx = threadIdx.x;   // 576
    if (idx < 576) {
        int t = idx / 64, cout = idx % 64;
        float s = 0.f;
        for (int cin = 0; cin < 64; ++cin)
            s += w2[(cout * 64 + cin) * 9 + t] * shift[cin];
        T[idx] = s;
    }
    __syncthreads();
    if (idx < 64) {
        float s = 0.f;
        for (int t = 0; t < 9; ++t) s += T[t * 64 + idx];
        T[576 + idx] = s;
    }
}

// ---------------------------------------------------------------------------
// Row-reuse conv 3x3 SAME, CIN->64, both operands in LDS via global_load_lds.
// Block = 4 waves; tile = 4 rows x 64 cols x 64 couts.
// Wave = 4 rows x 16-px window x 64 couts (acc[nt][row]).
// Per 32-cin chunk:
//   stage act (25.3 KB) + weights (36.9 KB) into LDS via gload_lds
//   __syncthreads (drain)
//   preload 18 act frags (row 0..5 x dx 0..2) into 72 VGPRs (each feeds up
//   to 3 taps -> 2x fewer act reads than tap-major)
//   9-tap loop: 4 wt ds_reads + 16 MFMA per tap (NO global loads in compute)
//   __syncthreads
// LDS 64,256 B -> 2 blocks/CU. Fused BN-stats epilogue.
// ---------------------------------------------------------------------------
template <int CIN, bool HAS_T, int HH, int WW>
__global__ __launch_bounds__(256, 2) void conv_mfma11_kernel(
    const ushort_t* __restrict__ X,    // NHWC bf16 [N*H*W][CIN]
    const ushort_t* __restrict__ Wsw,  // [KC][9][4][64][8]
    const float* __restrict__ T,       // [9*64 + 64] or null
    const float* __restrict__ bias,    // [64]
    ushort_t* __restrict__ Y,          // NHWC bf16 [N*H*W][64]
    float* __restrict__ stats)         // [32][128]
{
    constexpr int KC     = CIN >> 5;
    constexpr int COLS_B = WW >> 6;
    constexpr int ROWS_B = HH >> 2;

    __shared__ char smem[64256];
    // act @0 (25344: plane-major [4][396 px][8ch]), wt @25344 (36864),
    // sred @62208 (2048)
    ushort_t* actL = (ushort_t*)smem;
    ushort_t* wtL  = (ushort_t*)(smem + 25344);
    float (*sred)[128] = (float(*)[128])(smem + 62208);

    int nwg = gridDim.x, bid = blockIdx.x, cpx = nwg >> 3;
    int bs = (bid & 7) * cpx + (bid >> 3);   // XCD-contiguous swizzle

    int tid = threadIdx.x, wave = tid >> 6, lane = tid & 63;
    int lp = lane & 15, lg = lane >> 4;
    int wbase16 = (tid & 192) * 16;          // wave*64 quads * 16 B

    int tmp = bs;
    int ctile = tmp % COLS_B; tmp /= COLS_B;
    int rtile = tmp % ROWS_B;
    int n = tmp / ROWS_B;
    int y0 = rtile << 2, x0 = ctile << 6;

    // ---- act staging descriptors (1584 quads, 7/thread, masked) ----
    uint32 agoff[7];
    uint32 amask = 0;
#pragma unroll
    for (int j = 0; j < 7; ++j) {
        int s = tid + j * 256;
        agoff[j] = 0;
        if (s < 1584) {
            int plane = s / 396;
            int px    = s - plane * 396;
            int ry    = px / 66;
            int cx    = px - ry * 66;
            int gy = y0 - 1 + ry, gx = x0 - 1 + cx;
            if (((unsigned)gy < (unsigned)HH) && ((unsigned)gx < (unsigned)WW)) {
                amask |= (1u << j);
                agoff[j] = (uint32)((((uint32)(n * HH + gy) * WW + gx) * CIN
                                     + plane * 8) * 2);
            } else {
                uint4 zz; zz.x = zz.y = zz.z = zz.w = 0u;
                *(uint4*)(smem + s * 16) = zz;   // persists: never overwritten
            }
        }
    }

    const char* Xb = (const char*)X;
    const char* Wb = (const char*)Wsw;

    f32x4 acc[4][4];   // [nt][row]
#pragma unroll
    for (int a = 0; a < 4; ++a)
#pragma unroll
        for (int b = 0; b < 4; ++b) acc[a][b] = (f32x4){0.f, 0.f, 0.f, 0.f};

#pragma unroll 1
    for (int c = 0; c < KC; ++c) {
        if (c) __syncthreads();   // all waves done reading previous chunk
        // ---- stage act chunk c ----
        uint32 ca = (uint32)c * 64u;
#pragma unroll
        for (int j = 0; j < 7; ++j) {
            if (amask & (1u << j))
                gload_lds16(Xb + agoff[j] + ca, smem + j * 4096 + wbase16);
        }
        // ---- stage weight chunk c (2304 quads = 9/thread, exact) ----
        uint32 cw = (uint32)c * 36864u;
#pragma unroll
        for (int j = 0; j < 9; ++j) {
            gload_lds16(Wb + cw + (uint32)(tid + j * 256) * 16u,
                        smem + 25344 + j * 4096 + wbase16);
        }
        __syncthreads();          // drain DMAs -> act+wt ready

        // ---- preload 18 act fragments (row-reuse cache) ----
        bf16x8 af[6][3];
#pragma unroll
        for (int fr = 0; fr < 6; ++fr)
#pragma unroll
            for (int dxi = 0; dxi < 3; ++dxi) {
                int px = fr * 66 + wave * 16 + lp + dxi;
                af[fr][dxi] = *(const bf16x8*)(actL + lg * 3168 + px * 8);
            }

        // ---- 9-tap loop: pure LDS wt reads + MFMA ----
#pragma unroll
        for (int t = 0; t < 9; ++t) {
            const int dyi = t / 3, dxi = t % 3;
            bf16x8 wf[4];
#pragma unroll
            for (int nt = 0; nt < 4; ++nt)
                wf[nt] = *(const bf16x8*)(wtL + ((t * 4 + nt) * 64 + lane) * 8);
#pragma unroll
            for (int r = 0; r < 4; ++r) {
#pragma unroll
                for (int nt = 0; nt < 4; ++nt)
                    acc[nt][r] = __builtin_amdgcn_mfma_f32_16x16x32_bf16(
                        wf[nt], af[r + dyi][dxi], acc[nt][r], 0, 0, 0);
            }
        }
    }
    __syncthreads();   // protect sred region (none, separate) + uniform exit

    // ---- epilogue: bias (+T border fix), store, fused stats ----
    int x = x0 + wave * 16 + lp;
    bool lft = (x == 0), rgt = (x == WW - 1);
    float s16[16], q16[16];
#pragma unroll
    for (int j = 0; j < 16; ++j) { s16[j] = 0.f; q16[j] = 0.f; }

#pragma unroll
    for (int r = 0; r < 4; ++r) {
        int y = y0 + r;
        bool top = (y == 0), bot = (y == HH - 1);
        bool edge = top | bot | lft | rgt;
        size_t pbase = ((size_t)(n * HH + y) * WW + x) * 64;
#pragma unroll
        for (int nt = 0; nt < 4; ++nt) {
            ushort_t ov[4];
#pragma unroll
            for (int rr = 0; rr < 4; ++rr) {
                int ch = nt * 16 + lg * 4 + rr;
                float o = acc[nt][r][rr] + bias[ch];
                if (HAS_T) {
                    o += T[576 + ch];
                    if (edge) {
#pragma unroll
                        for (int t = 0; t < 9; ++t) {
                            int dy = t / 3 - 1, dx = t % 3 - 1;
                            bool miss = (top && dy < 0) || (bot && dy > 0) ||
                                        (lft && dx < 0) || (rgt && dx > 0);
                            if (miss) o -= T[t * 64 + ch];
                        }
                    }
                }
                s16[nt * 4 + rr] += o;
                q16[nt * 4 + rr] += o * o;
                ov[rr] = f2bf(o);
            }
            *(ushort4*)(Y + pbase + nt * 16 + lg * 4) = *(ushort4*)ov;
        }
    }

#pragma unroll
    for (int off = 1; off < 16; off <<= 1)
#pragma unroll
        for (int j = 0; j < 16; ++j) {
            s16[j] += __shfl_xor(s16[j], off);
            q16[j] += __shfl_xor(q16[j], off);
        }
    if (lp == 0) {
#pragma unroll
        for (int nt = 0; nt < 4; ++nt)
#pragma unroll
            for (int rr = 0; rr < 4; ++rr) {
                int ch = nt * 16 + lg * 4 + rr;
                sred[wave][ch]      = s16[nt * 4 + rr];
                sred[wave][64 + ch] = q16[nt * 4 + rr];
            }
    }
    __syncthreads();
    if (tid < 128) {
        float tot = sred[0][tid] + sred[1][tid] + sred[2][tid] + sred[3][tid];
        atomicAdd(&stats[(bs & 31) * 128 + tid], tot);
    }
}

// ---------------------------------------------------------------------------
// BN2 + ReLU -> skip_con (NCHW fp32) + Haar DWT -> X3 (NHWC bf16, 256 ch)
// ---------------------------------------------------------------------------
__global__ __launch_bounds__(256) void bn2_dwt_skip_kernel(
    const ushort_t* __restrict__ X2, const float* __restrict__ scsh,
    float* __restrict__ skip,     // [4][64][512][512]
    ushort_t* __restrict__ X3)    // [4][256][256][256]
{
    __shared__ float v[128][65];
    int tid = threadIdx.x;
    int b = blockIdx.x;
    int n  = b >> 11;
    int r2 = b & 2047;
    int y0 = (r2 >> 3) << 1;
    int x0 = (r2 & 7) << 6;

#pragma unroll
    for (int k = 0; k < 4; ++k) {
        int q  = tid + k * 256;
        int px = q >> 3;
        int cb = (q & 7) * 8;
        int gy = y0 + (px >> 6);
        int gx = x0 + (px & 63);
        uint4 raw = *(const uint4*)(X2 + ((size_t)(n * 512 + gy) * 512 + gx) * 64 + cb);
        const ushort_t* up = (const ushort_t*)&raw;
#pragma unroll
        for (int j = 0; j < 8; ++j) {
            float f = bf2f(up[j]);
            float o = f * scsh[cb + j] + scsh[64 + cb + j];
            v[px][cb + j] = fmaxf(o, 0.f);
        }
    }
    __syncthreads();

    {
        int c = tid >> 2, sub = tid & 3;
#pragma unroll
        for (int rr = 0; rr < 2; ++rr) {
            float* orow = skip + ((size_t)(n * 64 + c) * 512 + (y0 + rr)) * 512 + x0;
#pragma unroll
            for (int qq = 0; qq < 4; ++qq) {
                int xb = qq * 16 + sub * 4;
                float4 w4;
                w4.x = v[rr * 64 + xb + 0][c];
                w4.y = v[rr * 64 + xb + 1][c];
                w4.z = v[rr * 64 + xb + 2][c];
                w4.w = v[rr * 64 + xb + 3][c];
                *(float4*)(orow + xb) = w4;
            }
        }
    }
    {
        int c = tid & 63, jj = tid >> 6;
        int yq = y0 >> 1, xq = x0 >> 1;
#pragma unroll
        for (int it = 0; it < 8; ++it) {
            int xl = jj * 8 + it;
            float x00 = v[2 * xl][c],      x01 = v[2 * xl + 1][c];
            float x10 = v[64 + 2 * xl][c], x11 = v[64 + 2 * xl + 1][c];
            float cA = (x00 + x01 + x10 + x11) * 0.5f;
            float cH = (x00 + x01 - x10 - x11) * 0.5f;
            float cV = (x00 - x01 + x10 - x11) * 0.5f;
            float cD = (x00 - x01 - x10 + x11) * 0.5f;
            ushort_t* dst = X3 + ((size_t)(n * 256 + yq) * 256 + xq + xl) * 256 + c;
            dst[0]   = f2bf(cA);
            dst[64]  = f2bf(cH);
            dst[128] = f2bf(cV);
            dst[192] = f2bf(cD);
        }
    }
}

// ---------------------------------------------------------------------------
// BN3 + ReLU -> dwt_out (NCHW fp32)
// ---------------------------------------------------------------------------
__global__ __launch_bounds__(256) void bn3_kernel(
    const ushort_t* __restrict__ X4, const float* __restrict__ scsh,
    float* __restrict__ out)   // [4][64][256][256]
{
    __shared__ float v[64][65];
    int tid = threadIdx.x;
    int b = blockIdx.x;
    int n  = b >> 10;
    int r2 = b & 1023;
    int y  = r2 >> 2;
    int x0 = (r2 & 3) << 6;

#pragma unroll
    for (int k = 0; k < 2; ++k) {
        int q  = tid + k * 256;
        int px = q >> 3;
        int cb = (q & 7) * 8;
        uint4 raw = *(const uint4*)(X4 + ((size_t)(n * 256 + y) * 256 + x0 + px) * 64 + cb);
        const ushort_t* up = (const ushort_t*)&raw;
#pragma unroll
        for (int j = 0; j < 8; ++j) {
            float f = bf2f(up[j]);
            float o = f * scsh[cb + j] + scsh[64 + cb + j];
            v[px][cb + j] = fmaxf(o, 0.f);
        }
    }
    __syncthreads();
    int c = tid >> 2, sub = tid & 3;
    float* orow = out + ((size_t)(n * 64 + c) * 256 + y) * 256 + x0;
#pragma unroll
    for (int qq = 0; qq < 4; ++qq) {
        int xb = qq * 16 + sub * 4;
        float4 w4;
        w4.x = v[xb + 0][c];
        w4.y = v[xb + 1][c];
        w4.z = v[xb + 2][c];
        w4.w = v[xb + 3][c];
        *(float4*)(orow + xb) = w4;
    }
}

// ---------------------------------------------------------------------------
extern "C" void kernel_launch(void* const* d_in, const int* in_sizes, int n_in,
                              void* d_out, int out_size, void* d_ws, size_t ws_size,
                              hipStream_t stream)
{
    const float* in  = (const float*)d_in[0];
    const float* w1  = (const float*)d_in[1];
    const float* b1  = (const float*)d_in[2];
    const float* g1  = (const float*)d_in[3];
    const float* be1 = (const float*)d_in[4];
    const float* w2  = (const float*)d_in[5];
    const float* b2  = (const float*)d_in[6];
    const float* g2  = (const float*)d_in[7];
    const float* be2 = (const float*)d_in[8];
    const float* w3  = (const float*)d_in[9];
    const float* b3  = (const float*)d_in[10];
    const float* g3  = (const float*)d_in[11];
    const float* be3 = (const float*)d_in[12];

    float* out     = (float*)d_out;
    float* dwt_out = out;              // 4*64*256*256
    float* skip    = out + 16777216;   // 4*64*512*512

    char* ws = (char*)d_ws;
    ushort_t* X1 = (ushort_t*)ws;                       // 134,217,728 B
    ushort_t* X2 = (ushort_t*)(ws + 134217728);         // 134,217,728 B
    ushort_t* P  = X2;                                  // im2col patches alias X2
    ushort_t* X3 = X1;                                  // reuse
    ushort_t* X4 = X2;                                  // reuse
    char* aux = ws + 268435456;
    float* stats1 = (float*)(aux);                      // 16384 B each
    float* stats2 = (float*)(aux + 16384);
    float* stats3 = (float*)(aux + 32768);
    float* scsh1  = (float*)(aux + 49152);
    float* scsh2  = (float*)(aux + 49664);
    float* scsh3  = (float*)(aux + 50176);
    float* T2     = (float*)(aux + 50688);              // 640 floats
    ushort_t* Wsw2 = (ushort_t*)(aux + 57344);          // 73,728 B
    ushort_t* Wsw3 = (ushort_t*)(aux + 131072);         // 294,912 B
    ushort_t* Wsw1 = (ushort_t*)(aux + 425984);         // 4,096 B

    hipMemsetAsync(aux, 0, 49152, stream);

    im2col1_kernel<<<4096, 256, 0, stream>>>(in, P);
    prepw1_kernel<<<8, 256, 0, stream>>>(w1, Wsw1);
    gemm1_kernel<<<4096, 256, 0, stream>>>(P, Wsw1, b1, X1, stats1);
    finalize_kernel<<<1, 64, 0, stream>>>(stats1, g1, be1, 1.f / 1048576.f, scsh1);
    prepw_kernel<<<144, 256, 0, stream>>>(w2, scsh1, Wsw2, 64);
    prepT_kernel<<<1, 576, 0, stream>>>(w2, scsh1 + 64, T2);

    conv_mfma11_kernel<64, true, 512, 512><<<4096, 256, 0, stream>>>(
        X1, Wsw2, T2, b2, X2, stats2);
    finalize_kernel<<<1, 64, 0, stream>>>(stats2, g2, be2, 1.f / 1048576.f, scsh2);

    bn2_dwt_skip_kernel<<<8192, 256, 0, stream>>>(X2, scsh2, skip, X3);

    prepw_kernel<<<576, 256, 0, stream>>>(w3, nullptr, Wsw3, 256);
    conv_mfma11_kernel<256, false, 256, 256><<<1024, 256, 0, stream>>>(
        X3, Wsw3, nullptr, b3, X4, stats3);
    finalize_kernel<<<1, 64, 0, stream>>>(stats3, g3, be3, 1.f / 262144.f, scsh3);

    bn3_kernel<<<4096, 256, 0, stream>>>(X4, scsh3, dwt_out);
}